// Round 3
// baseline (231.460 us; speedup 1.0000x reference)
//
#include <hip/hip_runtime.h>
#include <hip/hip_bf16.h>

typedef unsigned short u16;
typedef unsigned int u32;

#define T_TOK 16384
#define DIM   1024
#define NEXP  8

// ---------- workspace layout (bytes) ----------
#define XB_OFF     0
#define WB_OFF     33554432
#define CNT_OFF    50331648
#define LIST_OFF   50332160
#define WLIST_OFF  50856448

__device__ __forceinline__ u16 f2bf(float f) {
    u32 u = __float_as_uint(f);
    u += 0x7fff + ((u >> 16) & 1);   // round-to-nearest-even
    return (u16)(u >> 16);
}

__global__ __launch_bounds__(128) void k_zero(int* counts) {
    if (threadIdx.x < NEXP * 16) counts[threadIdx.x] = 0;
}

__global__ __launch_bounds__(256) void k_cvt(const float* __restrict__ in,
                                             u16* __restrict__ out, int n4) {
    int i = blockIdx.x * 256 + threadIdx.x;
    if (i >= n4) return;
    float4 v = reinterpret_cast<const float4*>(in)[i];
    ushort4 u;
    u.x = f2bf(v.x); u.y = f2bf(v.y); u.z = f2bf(v.z); u.w = f2bf(v.w);
    reinterpret_cast<ushort4*>(out)[i] = u;
}

#define RT_PB 32

__global__ __launch_bounds__(256) void k_router(
    const float* __restrict__ x, const float* __restrict__ gw,
    const float* __restrict__ gb, const float* __restrict__ eb,
    float* __restrict__ out, float* __restrict__ logits,
    u16* __restrict__ xb, int* __restrict__ counts,
    int* __restrict__ lists, float* __restrict__ wlists)
{
    const int tid  = threadIdx.x;
    const int lane = tid & 63;
    const int w    = tid >> 6;

    __shared__ int   s_sel0[RT_PB], s_sel1[RT_PB];
    __shared__ float s_w0[RT_PB],  s_w1[RT_PB];
    __shared__ int   s_lcnt[NEXP], s_gbase[NEXP];

    if (tid < NEXP) s_lcnt[tid] = 0;

    for (int i = 0; i < 8; ++i) {
        const int l = w * 8 + i;
        const int t = blockIdx.x * RT_PB + l;

        const float* xr = x + (size_t)t * DIM;
        float4 xs[4];
#pragma unroll
        for (int j = 0; j < 4; ++j)
            xs[j] = *reinterpret_cast<const float4*>(xr + (j * 64 + lane) * 4);

        float acc[NEXP];
#pragma unroll
        for (int e = 0; e < NEXP; ++e) {
            const float* gr = gw + e * DIM;
            float s = 0.f;
#pragma unroll
            for (int j = 0; j < 4; ++j) {
                float4 g = *reinterpret_cast<const float4*>(gr + (j * 64 + lane) * 4);
                s += xs[j].x * g.x + xs[j].y * g.y + xs[j].z * g.z + xs[j].w * g.w;
            }
            acc[e] = s;
        }
#pragma unroll
        for (int off = 1; off < 64; off <<= 1) {
#pragma unroll
            for (int e = 0; e < NEXP; ++e) acc[e] += __shfl_xor(acc[e], off);
        }
#pragma unroll
        for (int e = 0; e < NEXP; ++e) acc[e] += gb[e];

        int i0 = 0; float v0 = acc[0];
#pragma unroll
        for (int e = 1; e < NEXP; ++e) if (acc[e] > v0) { v0 = acc[e]; i0 = e; }
        int i1 = -1; float v1 = -3.4e38f;
#pragma unroll
        for (int e = 0; e < NEXP; ++e) if (e != i0 && acc[e] > v1) { v1 = acc[e]; i1 = e; }
        float e1  = __expf(v1 - v0);
        float inv = 1.f / (1.f + e1);
        float w0 = inv, w1 = e1 * inv;

        const float* b0 = eb + i0 * DIM;
        const float* b1 = eb + i1 * DIM;
        float* orow = out + (size_t)t * DIM;
        u16*   xrow = xb  + (size_t)t * DIM;
#pragma unroll
        for (int j = 0; j < 4; ++j) {
            int c = (j * 64 + lane) * 4;
            float4 v = xs[j];
            ushort4 u;
            u.x = f2bf(v.x); u.y = f2bf(v.y); u.z = f2bf(v.z); u.w = f2bf(v.w);
            *reinterpret_cast<ushort4*>(xrow + c) = u;
            float4 f0 = *reinterpret_cast<const float4*>(b0 + c);
            float4 f1 = *reinterpret_cast<const float4*>(b1 + c);
            float4 o;
            o.x = w0 * f0.x + w1 * f1.x;
            o.y = w0 * f0.y + w1 * f1.y;
            o.z = w0 * f0.z + w1 * f1.z;
            o.w = w0 * f0.w + w1 * f1.w;
            *reinterpret_cast<float4*>(orow + c) = o;
        }
        if (lane == 0) {
            float4 lo = make_float4(acc[0], acc[1], acc[2], acc[3]);
            float4 hi = make_float4(acc[4], acc[5], acc[6], acc[7]);
            *reinterpret_cast<float4*>(logits + (size_t)t * NEXP)     = lo;
            *reinterpret_cast<float4*>(logits + (size_t)t * NEXP + 4) = hi;
            s_sel0[l] = i0; s_sel1[l] = i1;
            s_w0[l] = w0;   s_w1[l] = w1;
        }
    }
    __syncthreads();

    int i0 = 0, i1 = 0, r0 = 0, r1 = 0;
    if (tid < RT_PB) {
        i0 = s_sel0[tid]; i1 = s_sel1[tid];
        r0 = atomicAdd(&s_lcnt[i0], 1);
        r1 = atomicAdd(&s_lcnt[i1], 1);
    }
    __syncthreads();
    if (tid < NEXP)
        s_gbase[tid] = atomicAdd(&counts[tid * 16], s_lcnt[tid]);
    __syncthreads();
    if (tid < RT_PB) {
        int t  = blockIdx.x * RT_PB + tid;
        int p0 = s_gbase[i0] + r0;
        int p1 = s_gbase[i1] + r1;
        lists[i0 * T_TOK + p0]  = t;  wlists[i0 * T_TOK + p0] = s_w0[tid];
        lists[i1 * T_TOK + p1]  = t;  wlists[i1 * T_TOK + p1] = s_w1[tid];
    }
}

// ======================= grouped GEMM v3: 256x256, 8-wave, 4-phase/K-tile
// counted-vmcnt schedule (T2 swizzle + T3/T4 counted waits + T5 setprio).
//
// LDS (u16): buffer b at b*32768; A_ks at ks*8192; B at +16384.
// half-tile = 256 rows x 32 k, contiguous 16KB -> linear gload_lds dest.
// swizzle: 16B chunk c of row r stored at cs=(c+(r>>1))&3 (read side);
// staging inverts it on the GLOBAL source address (LDS dest stays linear).
//
// Wait derivation (per-wave vmcnt, 2 loads per half-tile, stage order
// A_k0,B_k0,A_k1,B_k1 of K-tile t+1 during t's phases 0..3):
//   entering t: in-flight = t's {A_k1,B_k1} (4); t's k0 halves proven by
//   previous vmcnt(4). end-ph1: in-flight 8 -> vmcnt(4) proves t's k1
//   halves (needed ph2/3). end-ph3: in-flight 8 -> vmcnt(4) proves
//   t+1's k0 halves. Never 0 in main loop. t=15 peeled: vmcnt(0) mid.

typedef __attribute__((ext_vector_type(8))) short bf16x8;
typedef __attribute__((ext_vector_type(4))) float f32x4;

#define GLDS16(g, l) __builtin_amdgcn_global_load_lds( \
    (const __attribute__((address_space(1))) void*)(g), \
    (__attribute__((address_space(3))) void*)(l), 16, 0, 0)

#define BAR() __builtin_amdgcn_s_barrier()
#define PRIO1() __builtin_amdgcn_s_setprio(1)
#define PRIO0() __builtin_amdgcn_s_setprio(0)
#define VMW4() asm volatile("s_waitcnt vmcnt(4)" ::: "memory")
#define VMW0() asm volatile("s_waitcnt vmcnt(0)" ::: "memory")

__global__ __launch_bounds__(512, 2) void k_gemm(
    const u16* __restrict__ xb, const u16* __restrict__ wb,
    const int* __restrict__ counts, const int* __restrict__ lists,
    const float* __restrict__ wlists, float* __restrict__ out)
{
    __shared__ u16 lds[65536];   // 128 KiB

    // XCD swizzle: 2048 tiles, 256/XCD -> each XCD owns one expert's tiles
    const int bid = (blockIdx.x & 7) * 256 + (blockIdx.x >> 3);
    const int e   = bid >> 8;
    const int nt  = (bid >> 6) & 3;
    const int mt  = bid & 63;
    const int cnt = counts[e * 16];
    if (mt * 256 >= cnt) return;

    const int tid  = threadIdx.x;
    const int lane = tid & 63;
    const int wid  = tid >> 6;
    const int wm   = wid >> 2;   // 0..1
    const int wn   = wid & 3;    // 0..3
    const int listbase = e * T_TOK;

    // ---- staging map: thread covers row rh=l*128+(tid>>2), chunk cs=tid&3.
    // global chunk c = (cs - (rh>>1)) & 3 ; (rh>>1) == l*64+(tid>>3) == tid>>3 mod 4
    const int srow = tid >> 2;
    const int cA   = (((tid & 3) - (tid >> 3)) & 3) * 8;   // u16 offset in row
    int tokA[2];
#pragma unroll
    for (int l = 0; l < 2; ++l) {
        int slot = mt * 256 + l * 128 + srow;
        tokA[l] = lists[listbase + (slot < cnt ? slot : cnt - 1)];
    }
    const u16* srcA0 = xb + (size_t)tokA[0] * DIM + cA;
    const u16* srcA1 = xb + (size_t)tokA[1] * DIM + cA;
    const u16* srcB0 = wb + ((size_t)e << 20) + (size_t)(nt * 256 + srow) * DIM + cA;
    const u16* srcB1 = srcB0 + (size_t)128 * DIM;

#define STAGE_A(nb, ks, kk) do { \
    GLDS16(srcA0 + (kk) + (ks) * 32, &lds[(nb) * 32768 + (ks) * 8192 + wid * 512]); \
    GLDS16(srcA1 + (kk) + (ks) * 32, &lds[(nb) * 32768 + (ks) * 8192 + 4096 + wid * 512]); } while (0)
#define STAGE_B(nb, ks, kk) do { \
    GLDS16(srcB0 + (kk) + (ks) * 32, &lds[(nb) * 32768 + 16384 + (ks) * 8192 + wid * 512]); \
    GLDS16(srcB1 + (kk) + (ks) * 32, &lds[(nb) * 32768 + 16384 + (ks) * 8192 + 4096 + wid * 512]); } while (0)

    // ---- read map: row rh, want chunk c=lane>>4 -> cs=(c+(rh>>1))&3.
    // rh = (wm|wn)*base + mi*16 + (lane&15); mi*16, wm*128, wn*64 all ==0 mod 8
    const int cs8  = ((((lane >> 4) + ((lane >> 1) & 3)) & 3)) * 8;
    const int offA = (wm * 128 + (lane & 15)) * 32 + cs8;
    const int offB = 16384 + (wn * 64 + (lane & 15)) * 32 + cs8;

    bf16x8 Af[4], Bf[4];
    f32x4 acc[8][4];
#pragma unroll
    for (int mi = 0; mi < 8; ++mi)
#pragma unroll
        for (int ni = 0; ni < 4; ++ni) acc[mi][ni] = (f32x4)0.f;

#define LDA4(buf, ks, q) do { \
    Af[0] = *(const bf16x8*)&lds[(buf) * 32768 + (ks) * 8192 + ((q) * 4 + 0) * 512 + offA]; \
    Af[1] = *(const bf16x8*)&lds[(buf) * 32768 + (ks) * 8192 + ((q) * 4 + 1) * 512 + offA]; \
    Af[2] = *(const bf16x8*)&lds[(buf) * 32768 + (ks) * 8192 + ((q) * 4 + 2) * 512 + offA]; \
    Af[3] = *(const bf16x8*)&lds[(buf) * 32768 + (ks) * 8192 + ((q) * 4 + 3) * 512 + offA]; } while (0)
#define LDB4(buf, ks) do { \
    Bf[0] = *(const bf16x8*)&lds[(buf) * 32768 + (ks) * 8192 + 0 * 512 + offB]; \
    Bf[1] = *(const bf16x8*)&lds[(buf) * 32768 + (ks) * 8192 + 1 * 512 + offB]; \
    Bf[2] = *(const bf16x8*)&lds[(buf) * 32768 + (ks) * 8192 + 2 * 512 + offB]; \
    Bf[3] = *(const bf16x8*)&lds[(buf) * 32768 + (ks) * 8192 + 3 * 512 + offB]; } while (0)
#define MFMA_ROW(q, i) do { \
    acc[(q)*4+(i)][0] = __builtin_amdgcn_mfma_f32_16x16x32_bf16(Af[i], Bf[0], acc[(q)*4+(i)][0], 0, 0, 0); \
    acc[(q)*4+(i)][1] = __builtin_amdgcn_mfma_f32_16x16x32_bf16(Af[i], Bf[1], acc[(q)*4+(i)][1], 0, 0, 0); \
    acc[(q)*4+(i)][2] = __builtin_amdgcn_mfma_f32_16x16x32_bf16(Af[i], Bf[2], acc[(q)*4+(i)][2], 0, 0, 0); \
    acc[(q)*4+(i)][3] = __builtin_amdgcn_mfma_f32_16x16x32_bf16(Af[i], Bf[3], acc[(q)*4+(i)][3], 0, 0, 0); } while (0)
#define MFMA16(q) do { MFMA_ROW(q, 0); MFMA_ROW(q, 1); MFMA_ROW(q, 2); MFMA_ROW(q, 3); } while (0)

    // prologue: stage K-tile 0 fully, drain once
    STAGE_A(0, 0, 0); STAGE_B(0, 0, 0); STAGE_A(0, 1, 0); STAGE_B(0, 1, 0);
    VMW0();
    BAR();

    for (int t = 0; t < 15; ++t) {
        const int buf = t & 1, nb = buf ^ 1;
        const int kn  = (t + 1) * 64;
        // ph0: ks0 quad0
        STAGE_A(nb, 0, kn);
        LDB4(buf, 0); LDA4(buf, 0, 0);
        BAR(); PRIO1(); MFMA16(0); PRIO0(); BAR();
        // ph1: ks0 quad1
        STAGE_B(nb, 0, kn);
        LDA4(buf, 0, 1);
        BAR(); PRIO1(); MFMA16(1); PRIO0();
        VMW4(); BAR();                       // proves t's k1 halves
        // ph2: ks1 quad0
        STAGE_A(nb, 1, kn);
        LDB4(buf, 1); LDA4(buf, 1, 0);
        BAR(); PRIO1(); MFMA16(0); PRIO0(); BAR();
        // ph3: ks1 quad1
        STAGE_B(nb, 1, kn);
        LDA4(buf, 1, 1);
        BAR(); PRIO1(); MFMA16(1); PRIO0();
        VMW4(); BAR();                       // proves t+1's k0 halves
    }
    {   // t = 15 peeled (buf 1), no staging
        LDB4(1, 0); LDA4(1, 0, 0);
        BAR(); PRIO1(); MFMA16(0); PRIO0(); BAR();
        LDA4(1, 0, 1);
        BAR(); PRIO1(); MFMA16(1); PRIO0();
        VMW0(); BAR();                       // proves t15's k1 halves
        LDB4(1, 1); LDA4(1, 1, 0);
        BAR(); PRIO1(); MFMA16(0); PRIO0(); BAR();
        LDA4(1, 1, 1);
        BAR(); PRIO1(); MFMA16(1); PRIO0();
    }

    // epilogue: C/D layout col=lane&15, row=(lane>>4)*4+reg
    const int rbase = (lane >> 4) * 4;
    const int cbase = nt * 256 + wn * 64 + (lane & 15);
#pragma unroll
    for (int mi = 0; mi < 8; ++mi) {
#pragma unroll
        for (int r = 0; r < 4; ++r) {
            int slot = mt * 256 + wm * 128 + mi * 16 + rbase + r;
            if (slot < cnt) {
                int   tok = lists[listbase + slot];
                float wgt = wlists[listbase + slot];
                float* orow = out + (size_t)tok * DIM + cbase;
#pragma unroll
                for (int ni = 0; ni < 4; ++ni)
                    atomicAdd(orow + ni * 16, acc[mi][ni][r] * wgt);
            }
        }
    }
}

extern "C" void kernel_launch(void* const* d_in, const int* in_sizes, int n_in,
                              void* d_out, int out_size, void* d_ws, size_t ws_size,
                              hipStream_t stream) {
    const float* x  = (const float*)d_in[0];
    const float* gw = (const float*)d_in[1];
    const float* gb = (const float*)d_in[2];
    const float* ew = (const float*)d_in[3];
    const float* eb = (const float*)d_in[4];

    float* out    = (float*)d_out;
    float* logits = out + (size_t)T_TOK * DIM;

    char* ws      = (char*)d_ws;
    u16*  xb      = (u16*)(ws + XB_OFF);
    u16*  wb      = (u16*)(ws + WB_OFF);
    int*  counts  = (int*)(ws + CNT_OFF);
    int*  lists   = (int*)(ws + LIST_OFF);
    float* wlists = (float*)(ws + WLIST_OFF);

    k_zero<<<1, 128, 0, stream>>>(counts);
    k_cvt<<<(NEXP * DIM * DIM / 4 + 255) / 256, 256, 0, stream>>>(ew, wb, NEXP * DIM * DIM / 4);
    k_router<<<T_TOK / RT_PB, 256, 0, stream>>>(x, gw, gb, eb, out, logits, xb, counts, lists, wlists);
    k_gemm<<<NEXP * 64 * 4, 512, 0, stream>>>(xb, wb, counts, lists, wlists, out);
}

// Round 4
// 175.868 us; speedup vs baseline: 1.3161x; 1.3161x over previous
//
#include <hip/hip_runtime.h>
#include <hip/hip_bf16.h>

typedef unsigned short u16;
typedef unsigned int u32;

#define T_TOK 16384
#define DIM   1024
#define NEXP  8

// ---------- workspace layout (bytes) ----------
// xb      : T*D*2            = 33,554,432
// wb      : E*D*D*2          = 16,777,216
// counts  : 8 ints @64B      = 512
// lists   : E*T*4            = 524,288   (value = tok*2 + k)
// selw    : T*16 (float4)    = 262,144   (e0,e1 bits, w0, w1)
// contrib : T*2*D*2 (bf16)   = 67,108,864
#define XB_OFF      0
#define WB_OFF      33554432
#define CNT_OFF     50331648
#define LIST_OFF    50332160
#define SELW_OFF    50856448
#define CONTRIB_OFF 51380736
#define WS_NEED     118489600ULL

__device__ __forceinline__ u16 f2bf(float f) {
    u32 u = __float_as_uint(f);
    u += 0x7fff + ((u >> 16) & 1);   // round-to-nearest-even
    return (u16)(u >> 16);
}
__device__ __forceinline__ float bf2f(u16 u) {
    return __uint_as_float(((u32)u) << 16);
}

__global__ __launch_bounds__(128) void k_zero(int* counts) {
    if (threadIdx.x < NEXP * 16) counts[threadIdx.x] = 0;
}

__global__ __launch_bounds__(256) void k_cvt(const float* __restrict__ in,
                                             u16* __restrict__ out, int n4) {
    int i = blockIdx.x * 256 + threadIdx.x;
    if (i >= n4) return;
    float4 v = reinterpret_cast<const float4*>(in)[i];
    ushort4 u;
    u.x = f2bf(v.x); u.y = f2bf(v.y); u.z = f2bf(v.z); u.w = f2bf(v.w);
    reinterpret_cast<ushort4*>(out)[i] = u;
}

// Router: logits (fp32), top-2, x->bf16, per-expert lists (value tok*2+k),
// per-token selw = {e0,e1,w0,w1}. One global atomic per expert per block.
#define RT_PB 32

__global__ __launch_bounds__(256) void k_router(
    const float* __restrict__ x, const float* __restrict__ gw,
    const float* __restrict__ gb, float* __restrict__ logits,
    u16* __restrict__ xb, int* __restrict__ counts,
    int* __restrict__ lists, float4* __restrict__ selw)
{
    const int tid  = threadIdx.x;
    const int lane = tid & 63;
    const int w    = tid >> 6;

    __shared__ int   s_sel0[RT_PB], s_sel1[RT_PB];
    __shared__ int   s_lcnt[NEXP], s_gbase[NEXP];

    if (tid < NEXP) s_lcnt[tid] = 0;

    for (int i = 0; i < 8; ++i) {
        const int l = w * 8 + i;
        const int t = blockIdx.x * RT_PB + l;

        const float* xr = x + (size_t)t * DIM;
        float4 xs[4];
#pragma unroll
        for (int j = 0; j < 4; ++j)
            xs[j] = *reinterpret_cast<const float4*>(xr + (j * 64 + lane) * 4);

        float acc[NEXP];
#pragma unroll
        for (int e = 0; e < NEXP; ++e) {
            const float* gr = gw + e * DIM;
            float s = 0.f;
#pragma unroll
            for (int j = 0; j < 4; ++j) {
                float4 g = *reinterpret_cast<const float4*>(gr + (j * 64 + lane) * 4);
                s += xs[j].x * g.x + xs[j].y * g.y + xs[j].z * g.z + xs[j].w * g.w;
            }
            acc[e] = s;
        }
#pragma unroll
        for (int off = 1; off < 64; off <<= 1) {
#pragma unroll
            for (int e = 0; e < NEXP; ++e) acc[e] += __shfl_xor(acc[e], off);
        }
#pragma unroll
        for (int e = 0; e < NEXP; ++e) acc[e] += gb[e];

        int i0 = 0; float v0 = acc[0];
#pragma unroll
        for (int e = 1; e < NEXP; ++e) if (acc[e] > v0) { v0 = acc[e]; i0 = e; }
        int i1 = -1; float v1 = -3.4e38f;
#pragma unroll
        for (int e = 0; e < NEXP; ++e) if (e != i0 && acc[e] > v1) { v1 = acc[e]; i1 = e; }
        float e1  = __expf(v1 - v0);
        float inv = 1.f / (1.f + e1);
        float w0 = inv, w1 = e1 * inv;

        u16* xrow = xb + (size_t)t * DIM;
#pragma unroll
        for (int j = 0; j < 4; ++j) {
            int c = (j * 64 + lane) * 4;
            float4 v = xs[j];
            ushort4 u;
            u.x = f2bf(v.x); u.y = f2bf(v.y); u.z = f2bf(v.z); u.w = f2bf(v.w);
            *reinterpret_cast<ushort4*>(xrow + c) = u;
        }
        if (lane == 0) {
            float4 lo = make_float4(acc[0], acc[1], acc[2], acc[3]);
            float4 hi = make_float4(acc[4], acc[5], acc[6], acc[7]);
            *reinterpret_cast<float4*>(logits + (size_t)t * NEXP)     = lo;
            *reinterpret_cast<float4*>(logits + (size_t)t * NEXP + 4) = hi;
            selw[t] = make_float4(__int_as_float(i0), __int_as_float(i1), w0, w1);
            s_sel0[l] = i0; s_sel1[l] = i1;
        }
    }
    __syncthreads();

    int i0 = 0, i1 = 0, r0 = 0, r1 = 0;
    if (tid < RT_PB) {
        i0 = s_sel0[tid]; i1 = s_sel1[tid];
        r0 = atomicAdd(&s_lcnt[i0], 1);
        r1 = atomicAdd(&s_lcnt[i1], 1);
    }
    __syncthreads();
    if (tid < NEXP)
        s_gbase[tid] = atomicAdd(&counts[tid * 16], s_lcnt[tid]);
    __syncthreads();
    if (tid < RT_PB) {
        int t  = blockIdx.x * RT_PB + tid;
        lists[i0 * T_TOK + s_gbase[i0] + r0] = t * 2;
        lists[i1 * T_TOK + s_gbase[i1] + r1] = t * 2 + 1;
    }
}

// ======================= grouped GEMM: 256x256, 8-wave, 4-phase/K-tile,
// counted vmcnt, T2 swizzle, T5 setprio. Epilogue: ATOMIC=0 -> plain bf16
// stores to contrib[tok*2+k]; ATOMIC=1 -> legacy atomicAdd into out.

typedef __attribute__((ext_vector_type(8))) short bf16x8;
typedef __attribute__((ext_vector_type(4))) float f32x4;

#define GLDS16(g, l) __builtin_amdgcn_global_load_lds( \
    (const __attribute__((address_space(1))) void*)(g), \
    (__attribute__((address_space(3))) void*)(l), 16, 0, 0)

#define BAR() __builtin_amdgcn_s_barrier()
#define PRIO1() __builtin_amdgcn_s_setprio(1)
#define PRIO0() __builtin_amdgcn_s_setprio(0)
#define VMW4() asm volatile("s_waitcnt vmcnt(4)" ::: "memory")
#define VMW0() asm volatile("s_waitcnt vmcnt(0)" ::: "memory")

template<int ATOMIC>
__global__ __launch_bounds__(512, 2) void k_gemm(
    const u16* __restrict__ xb, const u16* __restrict__ wb,
    const int* __restrict__ counts, const int* __restrict__ lists,
    const float4* __restrict__ selw, u16* __restrict__ contrib,
    float* __restrict__ out)
{
    __shared__ u16 lds[65536];   // 128 KiB

    const int bid = (blockIdx.x & 7) * 256 + (blockIdx.x >> 3);
    const int e   = bid >> 8;
    const int nt  = (bid >> 6) & 3;
    const int mt  = bid & 63;
    const int cnt = counts[e * 16];
    if (mt * 256 >= cnt) return;

    const int tid  = threadIdx.x;
    const int lane = tid & 63;
    const int wid  = tid >> 6;
    const int wm   = wid >> 2;
    const int wn   = wid & 3;
    const int listbase = e * T_TOK;

    const int srow = tid >> 2;
    const int cA   = (((tid & 3) - (tid >> 3)) & 3) * 8;
    int tokA[2];
#pragma unroll
    for (int l = 0; l < 2; ++l) {
        int slot = mt * 256 + l * 128 + srow;
        tokA[l] = lists[listbase + (slot < cnt ? slot : cnt - 1)] >> 1;
    }
    const u16* srcA0 = xb + (size_t)tokA[0] * DIM + cA;
    const u16* srcA1 = xb + (size_t)tokA[1] * DIM + cA;
    const u16* srcB0 = wb + ((size_t)e << 20) + (size_t)(nt * 256 + srow) * DIM + cA;
    const u16* srcB1 = srcB0 + (size_t)128 * DIM;

#define STAGE_A(nb, ks, kk) do { \
    GLDS16(srcA0 + (kk) + (ks) * 32, &lds[(nb) * 32768 + (ks) * 8192 + wid * 512]); \
    GLDS16(srcA1 + (kk) + (ks) * 32, &lds[(nb) * 32768 + (ks) * 8192 + 4096 + wid * 512]); } while (0)
#define STAGE_B(nb, ks, kk) do { \
    GLDS16(srcB0 + (kk) + (ks) * 32, &lds[(nb) * 32768 + 16384 + (ks) * 8192 + wid * 512]); \
    GLDS16(srcB1 + (kk) + (ks) * 32, &lds[(nb) * 32768 + 16384 + (ks) * 8192 + 4096 + wid * 512]); } while (0)

    const int cs8  = ((((lane >> 4) + ((lane >> 1) & 3)) & 3)) * 8;
    const int offA = (wm * 128 + (lane & 15)) * 32 + cs8;
    const int offB = 16384 + (wn * 64 + (lane & 15)) * 32 + cs8;

    bf16x8 Af[4], Bf[4];
    f32x4 acc[8][4];
#pragma unroll
    for (int mi = 0; mi < 8; ++mi)
#pragma unroll
        for (int ni = 0; ni < 4; ++ni) acc[mi][ni] = (f32x4)0.f;

#define LDA4(buf, ks, q) do { \
    Af[0] = *(const bf16x8*)&lds[(buf) * 32768 + (ks) * 8192 + ((q) * 4 + 0) * 512 + offA]; \
    Af[1] = *(const bf16x8*)&lds[(buf) * 32768 + (ks) * 8192 + ((q) * 4 + 1) * 512 + offA]; \
    Af[2] = *(const bf16x8*)&lds[(buf) * 32768 + (ks) * 8192 + ((q) * 4 + 2) * 512 + offA]; \
    Af[3] = *(const bf16x8*)&lds[(buf) * 32768 + (ks) * 8192 + ((q) * 4 + 3) * 512 + offA]; } while (0)
#define LDB4(buf, ks) do { \
    Bf[0] = *(const bf16x8*)&lds[(buf) * 32768 + (ks) * 8192 + 0 * 512 + offB]; \
    Bf[1] = *(const bf16x8*)&lds[(buf) * 32768 + (ks) * 8192 + 1 * 512 + offB]; \
    Bf[2] = *(const bf16x8*)&lds[(buf) * 32768 + (ks) * 8192 + 2 * 512 + offB]; \
    Bf[3] = *(const bf16x8*)&lds[(buf) * 32768 + (ks) * 8192 + 3 * 512 + offB]; } while (0)
#define MFMA_ROW(q, i) do { \
    acc[(q)*4+(i)][0] = __builtin_amdgcn_mfma_f32_16x16x32_bf16(Af[i], Bf[0], acc[(q)*4+(i)][0], 0, 0, 0); \
    acc[(q)*4+(i)][1] = __builtin_amdgcn_mfma_f32_16x16x32_bf16(Af[i], Bf[1], acc[(q)*4+(i)][1], 0, 0, 0); \
    acc[(q)*4+(i)][2] = __builtin_amdgcn_mfma_f32_16x16x32_bf16(Af[i], Bf[2], acc[(q)*4+(i)][2], 0, 0, 0); \
    acc[(q)*4+(i)][3] = __builtin_amdgcn_mfma_f32_16x16x32_bf16(Af[i], Bf[3], acc[(q)*4+(i)][3], 0, 0, 0); } while (0)
#define MFMA16(q) do { MFMA_ROW(q, 0); MFMA_ROW(q, 1); MFMA_ROW(q, 2); MFMA_ROW(q, 3); } while (0)

    STAGE_A(0, 0, 0); STAGE_B(0, 0, 0); STAGE_A(0, 1, 0); STAGE_B(0, 1, 0);
    VMW0();
    BAR();

    for (int t = 0; t < 15; ++t) {
        const int buf = t & 1, nb = buf ^ 1;
        const int kn  = (t + 1) * 64;
        STAGE_A(nb, 0, kn);
        LDB4(buf, 0); LDA4(buf, 0, 0);
        BAR(); PRIO1(); MFMA16(0); PRIO0(); BAR();
        STAGE_B(nb, 0, kn);
        LDA4(buf, 0, 1);
        BAR(); PRIO1(); MFMA16(1); PRIO0();
        VMW4(); BAR();
        STAGE_A(nb, 1, kn);
        LDB4(buf, 1); LDA4(buf, 1, 0);
        BAR(); PRIO1(); MFMA16(0); PRIO0(); BAR();
        STAGE_B(nb, 1, kn);
        LDA4(buf, 1, 1);
        BAR(); PRIO1(); MFMA16(1); PRIO0();
        VMW4(); BAR();
    }
    {
        LDB4(1, 0); LDA4(1, 0, 0);
        BAR(); PRIO1(); MFMA16(0); PRIO0(); BAR();
        LDA4(1, 0, 1);
        BAR(); PRIO1(); MFMA16(1); PRIO0();
        VMW0(); BAR();
        LDB4(1, 1); LDA4(1, 1, 0);
        BAR(); PRIO1(); MFMA16(0); PRIO0(); BAR();
        LDA4(1, 1, 1);
        BAR(); PRIO1(); MFMA16(1); PRIO0();
    }

    // epilogue: C/D layout col=lane&15, row=(lane>>4)*4+reg
    const int rbase = (lane >> 4) * 4;
    const int cbase = nt * 256 + wn * 64 + (lane & 15);
#pragma unroll
    for (int mi = 0; mi < 8; ++mi) {
#pragma unroll
        for (int r = 0; r < 4; ++r) {
            int slot = mt * 256 + wm * 128 + mi * 16 + rbase + r;
            if (slot < cnt) {
                int lv = lists[listbase + slot];
                if (ATOMIC) {
                    int tok = lv >> 1;
                    float4 sw = selw[tok];
                    float wgt = (lv & 1) ? sw.w : sw.z;
                    float* orow = out + (size_t)tok * DIM + cbase;
#pragma unroll
                    for (int ni = 0; ni < 4; ++ni)
                        atomicAdd(orow + ni * 16, acc[mi][ni][r] * wgt);
                } else {
                    u16* crow = contrib + (size_t)lv * DIM + cbase;
#pragma unroll
                    for (int ni = 0; ni < 4; ++ni)
                        crow[ni * 16] = f2bf(acc[mi][ni][r]);
                }
            }
        }
    }
}

// out[t] = w0*(c0 + b[e0]) + w1*(c1 + b[e1]); 4 tokens/block
__global__ __launch_bounds__(256) void k_combine(
    const u16* __restrict__ contrib, const float4* __restrict__ selw,
    const float* __restrict__ eb, float* __restrict__ out)
{
    const int lane = threadIdx.x & 63;
    const int t    = blockIdx.x * 4 + (threadIdx.x >> 6);
    float4 sw = selw[t];
    const int e0 = __float_as_int(sw.x);
    const int e1 = __float_as_int(sw.y);
    const float w0 = sw.z, w1 = sw.w;
    const u16* c0 = contrib + (size_t)(t * 2) * DIM;
    const u16* c1 = c0 + DIM;
    const float* b0 = eb + e0 * DIM;
    const float* b1 = eb + e1 * DIM;
    float* orow = out + (size_t)t * DIM;
#pragma unroll
    for (int j = 0; j < 2; ++j) {
        const int c = (j * 64 + lane) * 8;
        uint4 u0 = *reinterpret_cast<const uint4*>(c0 + c);
        uint4 u1 = *reinterpret_cast<const uint4*>(c1 + c);
        const u16* p0 = (const u16*)&u0;
        const u16* p1 = (const u16*)&u1;
        float4 r0, r1;
#pragma unroll
        for (int h = 0; h < 2; ++h) {
            float4 bb0 = *reinterpret_cast<const float4*>(b0 + c + h * 4);
            float4 bb1 = *reinterpret_cast<const float4*>(b1 + c + h * 4);
            float4 o;
            o.x = w0 * (bf2f(p0[h*4+0]) + bb0.x) + w1 * (bf2f(p1[h*4+0]) + bb1.x);
            o.y = w0 * (bf2f(p0[h*4+1]) + bb0.y) + w1 * (bf2f(p1[h*4+1]) + bb1.y);
            o.z = w0 * (bf2f(p0[h*4+2]) + bb0.z) + w1 * (bf2f(p1[h*4+2]) + bb1.z);
            o.w = w0 * (bf2f(p0[h*4+3]) + bb0.w) + w1 * (bf2f(p1[h*4+3]) + bb1.w);
            *reinterpret_cast<float4*>(orow + c + h * 4) = o;
        }
        (void)r0; (void)r1;
    }
}

// fallback bias-init when ws too small for contrib
__global__ __launch_bounds__(256) void k_bias(
    const float4* __restrict__ selw, const float* __restrict__ eb,
    float* __restrict__ out)
{
    const int lane = threadIdx.x & 63;
    const int t    = blockIdx.x * 4 + (threadIdx.x >> 6);
    float4 sw = selw[t];
    const float* b0 = eb + __float_as_int(sw.x) * DIM;
    const float* b1 = eb + __float_as_int(sw.y) * DIM;
    float* orow = out + (size_t)t * DIM;
#pragma unroll
    for (int j = 0; j < 4; ++j) {
        int c = (j * 64 + lane) * 4;
        float4 f0 = *reinterpret_cast<const float4*>(b0 + c);
        float4 f1 = *reinterpret_cast<const float4*>(b1 + c);
        float4 o;
        o.x = sw.z * f0.x + sw.w * f1.x;
        o.y = sw.z * f0.y + sw.w * f1.y;
        o.z = sw.z * f0.z + sw.w * f1.z;
        o.w = sw.z * f0.w + sw.w * f1.w;
        *reinterpret_cast<float4*>(orow + c) = o;
    }
}

extern "C" void kernel_launch(void* const* d_in, const int* in_sizes, int n_in,
                              void* d_out, int out_size, void* d_ws, size_t ws_size,
                              hipStream_t stream) {
    const float* x  = (const float*)d_in[0];
    const float* gw = (const float*)d_in[1];
    const float* gb = (const float*)d_in[2];
    const float* ew = (const float*)d_in[3];
    const float* eb = (const float*)d_in[4];

    float* out    = (float*)d_out;
    float* logits = out + (size_t)T_TOK * DIM;

    char*   ws      = (char*)d_ws;
    u16*    xb      = (u16*)(ws + XB_OFF);
    u16*    wb      = (u16*)(ws + WB_OFF);
    int*    counts  = (int*)(ws + CNT_OFF);
    int*    lists   = (int*)(ws + LIST_OFF);
    float4* selw    = (float4*)(ws + SELW_OFF);
    u16*    contrib = (u16*)(ws + CONTRIB_OFF);

    k_zero<<<1, 128, 0, stream>>>(counts);
    k_cvt<<<(NEXP * DIM * DIM / 4 + 255) / 256, 256, 0, stream>>>(ew, wb, NEXP * DIM * DIM / 4);
    k_router<<<T_TOK / RT_PB, 256, 0, stream>>>(x, gw, gb, logits, xb, counts, lists, selw);

    if (ws_size >= WS_NEED) {
        k_gemm<0><<<NEXP * 64 * 4, 512, 0, stream>>>(xb, wb, counts, lists, selw, contrib, out);
        k_combine<<<T_TOK / 4, 256, 0, stream>>>(contrib, selw, eb, out);
    } else {
        k_bias<<<T_TOK / 4, 256, 0, stream>>>(selw, eb, out);
        k_gemm<1><<<NEXP * 64 * 4, 512, 0, stream>>>(xb, wb, counts, lists, selw, contrib, out);
    }
}